// Round 8
// baseline (119.218 us; speedup 1.0000x reference)
//
#include <hip/hip_runtime.h>
#include <cstddef>
#include <cstdint>

// Channel-interleaved SAT: sat[(y*1025 + x)*8 + c], y,x in [0,1025), c in [0,8).
// sat[y][x][c] = sum over rows<y, cols<x of channel c.
#define SATW 1025
#define W8   8200          // 1025 * 8 floats per y-row
#define NCH  8
#define STRIP 16           // f32 columns per colscan block (2 x-coords x 8 ch)
#define NSTRIP ((W8 + STRIP - 1) / STRIP)   // 513

// ---------------- Kernel A: row prefix sums, planar in -> interleaved out ----
// One block per y. 4 waves; wave w scans channels 2w and 2w+1 independently
// (chunked wave scan, f64 accumulate), stages to LDS, then a fully-coalesced
// float4 write of the 32.8 KB interleaved row.
__global__ __launch_bounds__(256) void rowscan_kernel(const float* __restrict__ in,
                                                      float* __restrict__ sat) {
    const int y    = blockIdx.x;
    const int t    = threadIdx.x;
    const int lane = t & 63;
    const int wv   = t >> 6;

    __shared__ float lds[NCH][1024];

    for (int k = 0; k < 2; ++k) {
        const int c = wv * 2 + k;
        const float4* r4 = (const float4*)(in + ((size_t)c * 1024 + y) * 1024);
        double chunkbase = 0.0;
#pragma unroll
        for (int j = 0; j < 4; ++j) {           // 4 chunks of 256 floats
            float4 a = r4[lane + 64 * j];       // coalesced per instruction
            double v0 = a.x, v1 = a.y, v2 = a.z, v3 = a.w;
            double s = v0 + v1 + v2 + v3;
            double ps = s;                      // inclusive scan of lane sums
#pragma unroll
            for (int off = 1; off < 64; off <<= 1) {
                double n = __shfl_up(ps, off, 64);
                if (lane >= off) ps += n;
            }
            double base = chunkbase + ps - s;   // exclusive prefix for this lane
            double p0 = base + v0, p1 = p0 + v1, p2 = p1 + v2, p3 = p2 + v3;
            ((float4*)lds[c])[lane + 64 * j] =
                make_float4((float)p0, (float)p1, (float)p2, (float)p3);
            chunkbase += __shfl(ps, 63, 64);    // chunk total broadcast
        }
    }
    __syncthreads();

    // Interleaved row write: flat f -> x = f>>3, c = f&7; val = x ? prefix[x-1] : 0
    float* orow = sat + (size_t)(y + 1) * W8;
    for (int f4 = t; f4 < W8 / 4; f4 += 256) {
        int f = f4 * 4;
        float4 o;
        float* po = (float*)&o;
#pragma unroll
        for (int j = 0; j < 4; ++j) {
            int ff = f + j;
            int x = ff >> 3, c = ff & 7;
            po[j] = x ? lds[c][x - 1] : 0.0f;   // 2-way LDS alias: free
        }
        ((float4*)orow)[f4] = o;                // coalesced global store
    }
}

// ---------------- Kernel B: register-resident column scan --------------------
// One 256-thread block owns a 16-f32-column strip for the FULL 1024-row
// height in registers (16 float4/lane = 64 data VGPRs, ~100 total -> 513
// blocks = 2 blocks/CU co-resident; R7's 32-float4 version capped at 1
// block/CU and measured ~26 us). Wave w: rows [256w, 256w+256). Lane
// (rg,q): rg=lane>>2 owns rows 256w+16rg..+15 at float4 slot q=lane&3.
// Phase 1: 16 independent 16B loads (ILP). Phase 2: per-lane f64 sum over
// its 16 rows, 4-step shuffle scan over rg, tiny LDS scan over 4 waves.
// Phase 3: re-walk registers adding f64 base, store f32.
__global__ __launch_bounds__(256) void colscan_block(float* __restrict__ sat) {
    const int t    = threadIdx.x;
    const int lane = t & 63;
    const int w    = t >> 6;         // wave 0..3
    const int rg   = lane >> 2;      // row sub-chunk 0..15
    const int q    = lane & 3;       // float4 slot 0..3
    const int c0   = blockIdx.x * STRIP + q * 4;
    const bool act = (c0 + 3) < W8;  // last strip: only q=0,1 active

    float* p0 = sat + (size_t)(1 + w * 256 + rg * 16) * W8 + c0;

    float4 v[16];
    if (act) {
#pragma unroll
        for (int k = 0; k < 16; ++k)
            v[k] = *(const float4*)(p0 + (size_t)k * W8);
    } else {
#pragma unroll
        for (int k = 0; k < 16; ++k) v[k] = make_float4(0.f, 0.f, 0.f, 0.f);
    }

    // per-lane f64 totals over its 16 contiguous rows
    double T0 = 0, T1 = 0, T2 = 0, T3 = 0;
#pragma unroll
    for (int k = 0; k < 16; ++k) {
        T0 += v[k].x; T1 += v[k].y; T2 += v[k].z; T3 += v[k].w;
    }

    // in-wave inclusive scan over rg (lanes with same q are 4 apart)
    double i0 = T0, i1 = T1, i2 = T2, i3 = T3;
#pragma unroll
    for (int s = 4; s <= 32; s <<= 1) {
        double a0 = __shfl_up(i0, s, 64), a1 = __shfl_up(i1, s, 64);
        double a2 = __shfl_up(i2, s, 64), a3 = __shfl_up(i3, s, 64);
        if (lane >= s) { i0 += a0; i1 += a1; i2 += a2; i3 += a3; }
    }
    double e0 = i0 - T0, e1 = i1 - T1, e2 = i2 - T2, e3 = i3 - T3;

    __shared__ double wt[4][4][4];   // [wave][q][comp] wave totals
    if (lane >= 60) {                // rg==15 lane holds the wave-inclusive total
        wt[w][q][0] = i0; wt[w][q][1] = i1; wt[w][q][2] = i2; wt[w][q][3] = i3;
    }
    __syncthreads();
    double b0 = e0, b1 = e1, b2 = e2, b3 = e3;
    for (int w2 = 0; w2 < w; ++w2) {
        b0 += wt[w2][q][0]; b1 += wt[w2][q][1];
        b2 += wt[w2][q][2]; b3 += wt[w2][q][3];
    }

    if (act) {
#pragma unroll
        for (int k = 0; k < 16; ++k) {
            b0 += v[k].x; b1 += v[k].y; b2 += v[k].z; b3 += v[k].w;
            *(float4*)(p0 + (size_t)k * W8) =
                make_float4((float)b0, (float)b1, (float)b2, (float)b3);
        }
    }

    // SAT row y=0 is zeros for this strip
    if (t < 4) {
        int cz = blockIdx.x * STRIP + t * 4;
        if (cz + 3 < W8) *(float4*)(sat + cz) = make_float4(0.f, 0.f, 0.f, 0.f);
    }
}

// ---------------- Kernel C: one wave per ROI, all 8 channels (f32 math) ------
// Lane<49 owns one 7x7 bin: 4 corners x 8 interleaved channels (2 float4 each).
// Adaptive bins OVERLAP (hi_b = ceil vs lo_{b+1} = floor), so the 196 corner
// points (14x14 boundary grid) are genuinely distinct — loads are at the floor.
__global__ __launch_bounds__(256) void pool_kernel(const float* __restrict__ sat,
                                                   const int* __restrict__ rois,
                                                   float* __restrict__ out,
                                                   int n_roi) {
    int lane = threadIdx.x & 63;
    int roi  = (blockIdx.x * blockDim.x + threadIdx.x) >> 6;
    if (roi >= n_roi) return;

    const int4 rv = ((const int4*)rois)[roi];   // [y0, x0, y1, x1] pixel coords
    int ymin = rv.x >> 5;                       // / FEAT_STRIDE(32)
    int xmin = rv.y >> 5;
    int Ly   = (rv.z >> 5) + 1 - ymin;
    int Lx   = (rv.w >> 5) + 1 - xmin;

    float acc[NCH];
#pragma unroll
    for (int c = 0; c < NCH; ++c) acc[c] = 0.0f;

    if (lane < 49) {
        int by = lane / 7;
        int bx = lane - by * 7;
        int ylo = ymin + (by * Ly) / 7;
        int yhi = ymin + ((by + 1) * Ly + 6) / 7;
        int xlo = xmin + (bx * Lx) / 7;
        int xhi = xmin + ((bx + 1) * Lx + 6) / 7;
        float inv = 1.0f / (float)((yhi - ylo) * (xhi - xlo));

        float4 a[2], b[2], c4[2], d[2];
        const float4* hh = (const float4*)(sat + ((size_t)yhi * SATW + xhi) * NCH);
        const float4* lh = (const float4*)(sat + ((size_t)ylo * SATW + xhi) * NCH);
        const float4* hl = (const float4*)(sat + ((size_t)yhi * SATW + xlo) * NCH);
        const float4* ll = (const float4*)(sat + ((size_t)ylo * SATW + xlo) * NCH);
        a[0] = hh[0]; a[1] = hh[1];
        b[0] = lh[0]; b[1] = lh[1];
        c4[0] = hl[0]; c4[1] = hl[1];
        d[0] = ll[0]; d[1] = ll[1];
        const float* fa = (const float*)a;
        const float* fb = (const float*)b;
        const float* fc = (const float*)c4;
        const float* fd = (const float*)d;
#pragma unroll
        for (int c = 0; c < NCH; ++c)
            acc[c] = (fa[c] - fb[c] - fc[c] + fd[c]) * inv;
    }

#pragma unroll
    for (int off = 32; off; off >>= 1) {
#pragma unroll
        for (int c = 0; c < NCH; ++c) acc[c] += __shfl_down(acc[c], off, 64);
    }

    if (lane == 0) {
        const float k = 1.0f / 49.0f;
        float4* po = (float4*)(out + (size_t)roi * NCH);
        po[0] = make_float4(acc[0] * k, acc[1] * k, acc[2] * k, acc[3] * k);
        po[1] = make_float4(acc[4] * k, acc[5] * k, acc[6] * k, acc[7] * k);
    }
}

extern "C" void kernel_launch(void* const* d_in, const int* in_sizes, int n_in,
                              void* d_out, int out_size, void* d_ws, size_t ws_size,
                              hipStream_t stream) {
    const float* conv = (const float*)d_in[0];   // (1, 8, 1024, 1024) f32
    const int*   rois = (const int*)d_in[1];     // (8192, 4) int32
    float*       out  = (float*)d_out;           // (8192, 2, 4) f32 flat
    int n_roi = in_sizes[1] / 4;

    float* sat = (float*)d_ws;                   // 1025*8200*4 = 33.6 MB

    rowscan_kernel<<<1024, 256, 0, stream>>>(conv, sat);
    colscan_block<<<NSTRIP, 256, 0, stream>>>(sat);
    pool_kernel<<<(n_roi + 3) / 4, 256, 0, stream>>>(sat, rois, out, n_roi);
}

// Round 9
// 114.047 us; speedup vs baseline: 1.0453x; 1.0453x over previous
//
#include <hip/hip_runtime.h>
#include <cstddef>
#include <cstdint>

// Channel-interleaved, LINE-ALIGNED SAT: sat[(y*1026 + x)*8 + c], y,x in
// [0,1025), c in [0,8). Row stride = 1026*8 f32 = 8208 f32 = 32832 B = 513
// full 64B lines (the unpadded 32800 B stride is NOT 64B-aligned: alternate
// rows line-split every 64B segment and false-share lines across blocks/XCDs).
#define SATW_PAD 1026
#define W8   8200          // used floats per y-row (1025 * 8)
#define W8P  8208          // padded floats per y-row (1026 * 8)
#define NCH  8
#define STRIP 16           // f32 columns per colscan block = exactly one 64B line/row
#define NSTRIP (W8P / STRIP)   // 513, exact

// ---------------- Kernel A: row prefix sums, planar in -> interleaved out ----
// One block per y. 4 waves; wave w scans channels 2w and 2w+1 independently
// (chunked wave scan, f64 accumulate), stages to LDS, then a fully-coalesced
// line-aligned float4 write of the interleaved row.
__global__ __launch_bounds__(256) void rowscan_kernel(const float* __restrict__ in,
                                                      float* __restrict__ sat) {
    const int y    = blockIdx.x;
    const int t    = threadIdx.x;
    const int lane = t & 63;
    const int wv   = t >> 6;

    __shared__ float lds[NCH][1024];

    for (int k = 0; k < 2; ++k) {
        const int c = wv * 2 + k;
        const float4* r4 = (const float4*)(in + ((size_t)c * 1024 + y) * 1024);
        double chunkbase = 0.0;
#pragma unroll
        for (int j = 0; j < 4; ++j) {           // 4 chunks of 256 floats
            float4 a = r4[lane + 64 * j];       // coalesced per instruction
            double v0 = a.x, v1 = a.y, v2 = a.z, v3 = a.w;
            double s = v0 + v1 + v2 + v3;
            double ps = s;                      // inclusive scan of lane sums
#pragma unroll
            for (int off = 1; off < 64; off <<= 1) {
                double n = __shfl_up(ps, off, 64);
                if (lane >= off) ps += n;
            }
            double base = chunkbase + ps - s;   // exclusive prefix for this lane
            double p0 = base + v0, p1 = p0 + v1, p2 = p1 + v2, p3 = p2 + v3;
            ((float4*)lds[c])[lane + 64 * j] =
                make_float4((float)p0, (float)p1, (float)p2, (float)p3);
            chunkbase += __shfl(ps, 63, 64);    // chunk total broadcast
        }
    }
    __syncthreads();

    // Interleaved row write: flat f -> x = f>>3, c = f&7;
    // val = (1<=x<=1024) ? prefix[x-1] : 0 (x==0 boundary, x==1025 pad)
    float* orow = sat + (size_t)(y + 1) * W8P;
    for (int f4 = t; f4 < W8P / 4; f4 += 256) {
        int f = f4 * 4;
        float4 o;
        float* po = (float*)&o;
#pragma unroll
        for (int j = 0; j < 4; ++j) {
            int ff = f + j;
            int x = ff >> 3, c = ff & 7;
            po[j] = (x >= 1 && x <= 1024) ? lds[c][x - 1] : 0.0f;
        }
        ((float4*)orow)[f4] = o;                // 64B-line-aligned store
    }
}

// ---------------- Kernel B: register-resident column scan --------------------
// One 256-thread block owns a 16-f32-column strip (= one private 64B line per
// row, no cross-block line sharing) for the FULL 1024-row height in registers
// (16 float4/lane). Wave w: rows [256w, 256w+256). Lane (rg,q): rg=lane>>2
// owns rows 256w+16rg..+15 at float4 slot q=lane&3. Phase 1: 16 independent
// 16B loads (ILP). Phase 2: per-lane f64 sum, 4-step shuffle scan over rg,
// tiny LDS scan over 4 waves. Phase 3: re-walk registers add f64 base, store.
__global__ __launch_bounds__(256) void colscan_block(float* __restrict__ sat) {
    const int t    = threadIdx.x;
    const int lane = t & 63;
    const int w    = t >> 6;         // wave 0..3
    const int rg   = lane >> 2;      // row sub-chunk 0..15
    const int q    = lane & 3;       // float4 slot 0..3
    const int c0   = blockIdx.x * STRIP + q * 4;   // always < W8P, 16B-aligned

    float* p0 = sat + (size_t)(1 + w * 256 + rg * 16) * W8P + c0;

    float4 v[16];
#pragma unroll
    for (int k = 0; k < 16; ++k)
        v[k] = *(const float4*)(p0 + (size_t)k * W8P);

    // per-lane f64 totals over its 16 contiguous rows
    double T0 = 0, T1 = 0, T2 = 0, T3 = 0;
#pragma unroll
    for (int k = 0; k < 16; ++k) {
        T0 += v[k].x; T1 += v[k].y; T2 += v[k].z; T3 += v[k].w;
    }

    // in-wave inclusive scan over rg (lanes with same q are 4 apart)
    double i0 = T0, i1 = T1, i2 = T2, i3 = T3;
#pragma unroll
    for (int s = 4; s <= 32; s <<= 1) {
        double a0 = __shfl_up(i0, s, 64), a1 = __shfl_up(i1, s, 64);
        double a2 = __shfl_up(i2, s, 64), a3 = __shfl_up(i3, s, 64);
        if (lane >= s) { i0 += a0; i1 += a1; i2 += a2; i3 += a3; }
    }
    double e0 = i0 - T0, e1 = i1 - T1, e2 = i2 - T2, e3 = i3 - T3;

    __shared__ double wt[4][4][4];   // [wave][q][comp] wave totals
    if (lane >= 60) {                // rg==15 lane holds the wave-inclusive total
        wt[w][q][0] = i0; wt[w][q][1] = i1; wt[w][q][2] = i2; wt[w][q][3] = i3;
    }
    __syncthreads();
    double b0 = e0, b1 = e1, b2 = e2, b3 = e3;
    for (int w2 = 0; w2 < w; ++w2) {
        b0 += wt[w2][q][0]; b1 += wt[w2][q][1];
        b2 += wt[w2][q][2]; b3 += wt[w2][q][3];
    }

#pragma unroll
    for (int k = 0; k < 16; ++k) {
        b0 += v[k].x; b1 += v[k].y; b2 += v[k].z; b3 += v[k].w;
        *(float4*)(p0 + (size_t)k * W8P) =
            make_float4((float)b0, (float)b1, (float)b2, (float)b3);
    }

    // SAT row y=0 is zeros for this strip
    if (t < 4) {
        int cz = blockIdx.x * STRIP + t * 4;
        *(float4*)(sat + cz) = make_float4(0.f, 0.f, 0.f, 0.f);
    }
}

// ---------------- Kernel C: one wave per ROI, all 8 channels (f32 math) ------
// Lane<49 owns one 7x7 bin: 4 corners x 8 interleaved channels (2 float4 each).
// Adaptive bins OVERLAP (hi_b = ceil vs lo_{b+1} = floor), so the 196 corner
// points (14x14 boundary grid) are genuinely distinct — loads are at the floor.
__global__ __launch_bounds__(256) void pool_kernel(const float* __restrict__ sat,
                                                   const int* __restrict__ rois,
                                                   float* __restrict__ out,
                                                   int n_roi) {
    int lane = threadIdx.x & 63;
    int roi  = (blockIdx.x * blockDim.x + threadIdx.x) >> 6;
    if (roi >= n_roi) return;

    const int4 rv = ((const int4*)rois)[roi];   // [y0, x0, y1, x1] pixel coords
    int ymin = rv.x >> 5;                       // / FEAT_STRIDE(32)
    int xmin = rv.y >> 5;
    int Ly   = (rv.z >> 5) + 1 - ymin;
    int Lx   = (rv.w >> 5) + 1 - xmin;

    float acc[NCH];
#pragma unroll
    for (int c = 0; c < NCH; ++c) acc[c] = 0.0f;

    if (lane < 49) {
        int by = lane / 7;
        int bx = lane - by * 7;
        int ylo = ymin + (by * Ly) / 7;
        int yhi = ymin + ((by + 1) * Ly + 6) / 7;
        int xlo = xmin + (bx * Lx) / 7;
        int xhi = xmin + ((bx + 1) * Lx + 6) / 7;
        float inv = 1.0f / (float)((yhi - ylo) * (xhi - xlo));

        float4 a[2], b[2], c4[2], d[2];
        const float4* hh = (const float4*)(sat + ((size_t)yhi * SATW_PAD + xhi) * NCH);
        const float4* lh = (const float4*)(sat + ((size_t)ylo * SATW_PAD + xhi) * NCH);
        const float4* hl = (const float4*)(sat + ((size_t)yhi * SATW_PAD + xlo) * NCH);
        const float4* ll = (const float4*)(sat + ((size_t)ylo * SATW_PAD + xlo) * NCH);
        a[0] = hh[0]; a[1] = hh[1];
        b[0] = lh[0]; b[1] = lh[1];
        c4[0] = hl[0]; c4[1] = hl[1];
        d[0] = ll[0]; d[1] = ll[1];
        const float* fa = (const float*)a;
        const float* fb = (const float*)b;
        const float* fc = (const float*)c4;
        const float* fd = (const float*)d;
#pragma unroll
        for (int c = 0; c < NCH; ++c)
            acc[c] = (fa[c] - fb[c] - fc[c] + fd[c]) * inv;
    }

#pragma unroll
    for (int off = 32; off; off >>= 1) {
#pragma unroll
        for (int c = 0; c < NCH; ++c) acc[c] += __shfl_down(acc[c], off, 64);
    }

    if (lane == 0) {
        const float k = 1.0f / 49.0f;
        float4* po = (float4*)(out + (size_t)roi * NCH);
        po[0] = make_float4(acc[0] * k, acc[1] * k, acc[2] * k, acc[3] * k);
        po[1] = make_float4(acc[4] * k, acc[5] * k, acc[6] * k, acc[7] * k);
    }
}

extern "C" void kernel_launch(void* const* d_in, const int* in_sizes, int n_in,
                              void* d_out, int out_size, void* d_ws, size_t ws_size,
                              hipStream_t stream) {
    const float* conv = (const float*)d_in[0];   // (1, 8, 1024, 1024) f32
    const int*   rois = (const int*)d_in[1];     // (8192, 4) int32
    float*       out  = (float*)d_out;           // (8192, 2, 4) f32 flat
    int n_roi = in_sizes[1] / 4;

    float* sat = (float*)d_ws;                   // 1025 * 8208 * 4 = 33.65 MB

    rowscan_kernel<<<1024, 256, 0, stream>>>(conv, sat);
    colscan_block<<<NSTRIP, 256, 0, stream>>>(sat);
    pool_kernel<<<(n_roi + 3) / 4, 256, 0, stream>>>(sat, rois, out, n_roi);
}